// Round 3
// baseline (523.791 us; speedup 1.0000x reference)
//
#include <hip/hip_runtime.h>
#include <hip/hip_bf16.h>

#define S_LEN 127
#define NB    32
#define HDIM  256
#define DH    64
#define SCALE_F 0.125f
#define GRID_X 1024
#define NTILE_GEMM 1016   // 127 row-tiles x 8 col-tiles (32x32 each)

typedef __bf16 bf16x8 __attribute__((ext_vector_type(8)));
typedef float  f32x4  __attribute__((ext_vector_type(4)));

// ---------------------------------------------------------------------------
// Per-wave 32x32 output tile of out[M,256] = A[M,256] @ W[256,256]^T + bias.
// (R1-proven layout: absmax 0.031.) K=256 -> 8 k-steps, 4 MFMA each... total
// 32 MFMA per wave, 64B/lane loads per k-step.
// ---------------------------------------------------------------------------
__device__ __forceinline__ void gemm_tile32(
    const float* __restrict__ A, const float* __restrict__ W,
    const float* __restrict__ bias, float* __restrict__ out,
    int row0, int col0)
{
  const int lane = threadIdx.x & 63;
  const int r  = lane & 15;
  const int ks = (lane >> 4) << 3;
  f32x4 acc[2][2] = {};
  const float* Ab = A + (size_t)row0 * HDIM + ks;
  const float* Wb = W + (size_t)col0 * HDIM + ks;
#pragma unroll
  for (int kb = 0; kb < HDIM; kb += 32) {
    bf16x8 af[2], wf[2];
#pragma unroll
    for (int mi = 0; mi < 2; ++mi) {
      const float* pa = Ab + (size_t)(mi * 16 + r) * HDIM + kb;
      const float* pw = Wb + (size_t)(mi * 16 + r) * HDIM + kb;
      const float4 a0 = *(const float4*)pa;
      const float4 a1 = *(const float4*)(pa + 4);
      const float4 w0 = *(const float4*)pw;
      const float4 w1 = *(const float4*)(pw + 4);
      af[mi][0]=(__bf16)a0.x; af[mi][1]=(__bf16)a0.y; af[mi][2]=(__bf16)a0.z; af[mi][3]=(__bf16)a0.w;
      af[mi][4]=(__bf16)a1.x; af[mi][5]=(__bf16)a1.y; af[mi][6]=(__bf16)a1.z; af[mi][7]=(__bf16)a1.w;
      wf[mi][0]=(__bf16)w0.x; wf[mi][1]=(__bf16)w0.y; wf[mi][2]=(__bf16)w0.z; wf[mi][3]=(__bf16)w0.w;
      wf[mi][4]=(__bf16)w1.x; wf[mi][5]=(__bf16)w1.y; wf[mi][6]=(__bf16)w1.z; wf[mi][7]=(__bf16)w1.w;
    }
#pragma unroll
    for (int mi = 0; mi < 2; ++mi)
#pragma unroll
      for (int ni = 0; ni < 2; ++ni)
        acc[mi][ni] = __builtin_amdgcn_mfma_f32_16x16x32_bf16(
            af[mi], wf[ni], acc[mi][ni], 0, 0, 0);
  }
  const int crow = (lane >> 4) * 4;
  const int ccol = lane & 15;
#pragma unroll
  for (int mi = 0; mi < 2; ++mi)
#pragma unroll
    for (int ni = 0; ni < 2; ++ni) {
      const int oc = col0 + ni * 16 + ccol;
      const float bv = bias[oc];
#pragma unroll
      for (int rg = 0; rg < 4; ++rg)
        out[(size_t)(row0 + mi * 16 + crow + rg) * HDIM + oc] = acc[mi][ni][rg] + bv;
    }
}

// Device-scope grid barrier. Safe because __launch_bounds__(256,4) guarantees
// 4 blocks/CU -> all 1024 blocks co-resident. Counters zeroed by memsetAsync
// before every launch. __threadfence() = agent-scope fence (wb/inv per-XCD L2).
__device__ __forceinline__ void grid_barrier(unsigned* cnt, unsigned target) {
  __threadfence();
  __syncthreads();
  if (threadIdx.x == 0) {
    atomicAdd(cnt, 1u);
    while (atomicAdd(cnt, 0u) < target) __builtin_amdgcn_s_sleep(2);
  }
  __syncthreads();
  __threadfence();
}

// ---------------------------------------------------------------------------
// Fully fused pipeline: [qkv proj] -> barrier -> [sparse attn] -> barrier ->
// [out proj]. 1024 blocks x 256 threads.
// ---------------------------------------------------------------------------
__global__ __launch_bounds__(256, 4) void fused_mha(
    const float* __restrict__ query, const float* __restrict__ key,
    const float* __restrict__ value, const int* __restrict__ graph,
    const float* __restrict__ ekt, const float* __restrict__ evt,
    const float* __restrict__ eqt,
    const float* __restrict__ Wq, const float* __restrict__ bq,
    const float* __restrict__ Wk, const float* __restrict__ bk,
    const float* __restrict__ Wv, const float* __restrict__ bv,
    const float* __restrict__ Wo, const float* __restrict__ bo,
    float* __restrict__ qp, float* __restrict__ kp, float* __restrict__ vp,
    float* __restrict__ xp, float* __restrict__ out, unsigned* __restrict__ cnt)
{
  const int w = threadIdx.x >> 6;
  const int l = threadIdx.x & 63;

  __shared__ int   s_list[S_LEN];
  __shared__ float s_attn[4][S_LEN];
  __shared__ int   s_cnt[2];

  // ================= Phase 1: q/k/v projections (3048 tile-waves) ==========
  {
    const int g = blockIdx.x * 4 + w;
    if (g < 3 * NTILE_GEMM) {
      const int pj = g / NTILE_GEMM;
      const int t  = g % NTILE_GEMM;
      const float* A; const float* W; const float* bias; float* o;
      if (pj == 0)      { A = query; W = Wq; bias = bq; o = qp; }
      else if (pj == 1) { A = key;   W = Wk; bias = bk; o = kp; }
      else              { A = value; W = Wv; bias = bv; o = vp; }
      gemm_tile32(A, W, bias, o, (t % 127) * 32, (t / 127) * 32);
    }
  }
  grid_barrier(&cnt[0], gridDim.x);

  // ================= Phase 2: sparse attention (4064 items) ================
  for (int it = blockIdx.x; it < NB * S_LEN; it += gridDim.x) {
    __syncthreads();  // protect s_list/s_attn reuse across items
    const int q = it % S_LEN;
    const int b = it / S_LEN;

    bool valid = false;
    const int k0 = w * 64 + l;
    if (w < 2 && k0 < S_LEN) {
      const int g = graph[((size_t)b * S_LEN + q) * S_LEN + k0];
      bool keep;
      if (q < 3 || k0 < 3) keep = true;
      else {
        const int blk = 3 + 2 * ((q - 3) >> 1);
        keep = (k0 >= blk) & (k0 < blk + 2);
      }
      valid = (g != 0) && keep;
    }
    const unsigned long long bal = __ballot(valid);
    if (w < 2 && l == 0) s_cnt[w] = (int)__popcll(bal);
    __syncthreads();
    int n = s_cnt[0] + s_cnt[1];
    if (valid) {
      const int pos = (int)__popcll(bal & ((1ull << l) - 1ull)) + (w ? s_cnt[0] : 0);
      s_list[pos] = k0;
    }
    __syncthreads();

    if (n == 0) {
      if (threadIdx.x < S_LEN) {
        s_list[threadIdx.x] = threadIdx.x;
        const float u = 1.0f / 127.0f;
        s_attn[0][threadIdx.x] = u; s_attn[1][threadIdx.x] = u;
        s_attn[2][threadIdx.x] = u; s_attn[3][threadIdx.x] = u;
      }
      n = S_LEN;
      __syncthreads();
    } else {
      const float* qrow = qp + ((size_t)b * S_LEN + q) * HDIM;
      const float  q0 = qrow[l], q1 = qrow[64 + l], q2 = qrow[128 + l], q3 = qrow[192 + l];
      const float* eqb = eqt + ((size_t)b * S_LEN * S_LEN + q) * DH;
      const float* ekb = ekt + ((size_t)(b * S_LEN + q)) * S_LEN * DH;
      const float* kpb = kp + (size_t)b * S_LEN * HDIM;

      float ceq = 0.f, cek = 0.f, ck0 = 0.f, ck1 = 0.f, ck2 = 0.f, ck3 = 0.f;
      if (w < n) {
        const int kk = s_list[w];
        ceq = eqb[(size_t)kk * (S_LEN * DH) + l];
        cek = ekb[kk * DH + l];
        const float* kr = kpb + (size_t)kk * HDIM;
        ck0 = kr[l]; ck1 = kr[64 + l]; ck2 = kr[128 + l]; ck3 = kr[192 + l];
      }
      for (int i0 = 0; i0 < n; i0 += 4) {
        const int i = i0 + w;
        float neq = 0.f, nek = 0.f, nk0 = 0.f, nk1 = 0.f, nk2 = 0.f, nk3 = 0.f;
        const int j = i + 4;
        if (j < n) {
          const int kk = s_list[j];
          neq = eqb[(size_t)kk * (S_LEN * DH) + l];
          nek = ekb[kk * DH + l];
          const float* kr = kpb + (size_t)kk * HDIM;
          nk0 = kr[l]; nk1 = kr[64 + l]; nk2 = kr[128 + l]; nk3 = kr[192 + l];
        }
        float p0 = (q0 + ceq) * (ck0 + cek);
        float p1 = (q1 + ceq) * (ck1 + cek);
        float p2 = (q2 + ceq) * (ck2 + cek);
        float p3 = (q3 + ceq) * (ck3 + cek);
#pragma unroll
        for (int off = 32; off; off >>= 1) {
          p0 += __shfl_xor(p0, off, 64);
          p1 += __shfl_xor(p1, off, 64);
          p2 += __shfl_xor(p2, off, 64);
          p3 += __shfl_xor(p3, off, 64);
        }
        if (i < n && l < 4) {
          const float s = (l == 0) ? p0 : (l == 1) ? p1 : (l == 2) ? p2 : p3;
          s_attn[l][i] = s * SCALE_F;
        }
        ceq = neq; cek = nek; ck0 = nk0; ck1 = nk1; ck2 = nk2; ck3 = nk3;
      }
      __syncthreads();

      {
        const float v0 = (l < n) ? s_attn[w][l] : -INFINITY;
        const float v1 = (64 + l < n) ? s_attn[w][64 + l] : -INFINITY;
        float mx = fmaxf(v0, v1);
#pragma unroll
        for (int off = 32; off; off >>= 1) mx = fmaxf(mx, __shfl_xor(mx, off, 64));
        const float e0 = (l < n) ? expf(v0 - mx) : 0.f;
        const float e1 = (64 + l < n) ? expf(v1 - mx) : 0.f;
        float sm = e0 + e1;
#pragma unroll
        for (int off = 32; off; off >>= 1) sm += __shfl_xor(sm, off, 64);
        const float inv = 1.0f / sm;
        if (l < n) s_attn[w][l] = e0 * inv;
        if (64 + l < n) s_attn[w][64 + l] = e1 * inv;
      }
      __syncthreads();
    }

    {
      const float* evb = evt + ((size_t)(b * S_LEN + q)) * S_LEN * DH;
      const float* vbp = vp + (size_t)b * S_LEN * HDIM + w * DH;
      float acc0 = 0.f, acc1 = 0.f;
      int i = 0;
      for (; i + 4 <= n; i += 4) {
        const int ka = s_list[i], kb2 = s_list[i + 1];
        const int kc = s_list[i + 2], kd = s_list[i + 3];
        const float aa = s_attn[w][i],     ab = s_attn[w][i + 1];
        const float ac = s_attn[w][i + 2], ad = s_attn[w][i + 3];
        const float va = vbp[(size_t)ka * HDIM + l],   ea = evb[ka * DH + l];
        const float vb2 = vbp[(size_t)kb2 * HDIM + l], eb = evb[kb2 * DH + l];
        const float vc = vbp[(size_t)kc * HDIM + l],   ec = evb[kc * DH + l];
        const float vd = vbp[(size_t)kd * HDIM + l],   ed = evb[kd * DH + l];
        acc0 += aa * (va + ea) + ab * (vb2 + eb);
        acc1 += ac * (vc + ec) + ad * (vd + ed);
      }
      for (; i < n; ++i) {
        const int kk = s_list[i];
        acc0 += s_attn[w][i] * (vbp[(size_t)kk * HDIM + l] + evb[kk * DH + l]);
      }
      xp[((size_t)b * S_LEN + q) * HDIM + threadIdx.x] = acc0 + acc1;
    }
  }
  grid_barrier(&cnt[1], gridDim.x);

  // ================= Phase 3: output projection (1016 tile-waves) ==========
  {
    const int g = blockIdx.x * 4 + w;
    if (g < NTILE_GEMM) {
      gemm_tile32(xp, Wo, bo, out, (g % 127) * 32, (g / 127) * 32);
    }
  }
}

extern "C" void kernel_launch(void* const* d_in, const int* in_sizes, int n_in,
                              void* d_out, int out_size, void* d_ws, size_t ws_size,
                              hipStream_t stream) {
  const float* query = (const float*)d_in[0];
  const float* key   = (const float*)d_in[1];
  const float* value = (const float*)d_in[2];
  const int*   graph = (const int*)d_in[3];
  const float* ekt   = (const float*)d_in[4];
  const float* evt   = (const float*)d_in[5];
  const float* eqt   = (const float*)d_in[6];
  const float* Wq = (const float*)d_in[7];  const float* bq = (const float*)d_in[8];
  const float* Wk = (const float*)d_in[9];  const float* bk = (const float*)d_in[10];
  const float* Wv = (const float*)d_in[11]; const float* bv = (const float*)d_in[12];
  const float* Wo = (const float*)d_in[13]; const float* bo = (const float*)d_in[14];
  float* out = (float*)d_out;

  // ws layout: [0,256) barrier counters; then qp/kp/vp/xp (f32, 4.16 MB each)
  unsigned* cnt = (unsigned*)d_ws;
  float* base = (float*)((char*)d_ws + 256);
  const size_t NTOK = (size_t)NB * S_LEN;  // 4064
  float* qp = base;
  float* kp = qp + NTOK * HDIM;
  float* vp = kp + NTOK * HDIM;
  float* xp = vp + NTOK * HDIM;

  hipMemsetAsync(cnt, 0, 256, stream);
  fused_mha<<<dim3(GRID_X), 256, 0, stream>>>(
      query, key, value, graph, ekt, evt, eqt,
      Wq, bq, Wk, bk, Wv, bv, Wo, bo,
      qp, kp, vp, xp, out, cnt);
}

// Round 4
// 62.827 us; speedup vs baseline: 8.3370x; 8.3370x over previous
//
#include <hip/hip_runtime.h>
#include <hip/hip_bf16.h>

#define S_LEN 127
#define NB    32
#define HDIM  256
#define DH    64
#define SCALE_F 0.125f

typedef __bf16 bf16x8 __attribute__((ext_vector_type(8)));
typedef float  f32x4  __attribute__((ext_vector_type(4)));

// ---------------------------------------------------------------------------
// Per-wave 32x32 output tile of out[M,256] = A[M,256] @ W[256,256]^T + bias.
// R1-proven fragment layout (absmax 0.031). K=256 -> 8 k-steps x 4 MFMA.
// 1-step k-lookahead register prefetch to hide L2/HBM latency.
// ---------------------------------------------------------------------------
__device__ __forceinline__ void gemm_tile32(
    const float* __restrict__ A, const float* __restrict__ W,
    const float* __restrict__ bias, float* __restrict__ out,
    int row0, int col0)
{
  const int lane = threadIdx.x & 63;
  const int r  = lane & 15;
  const int ks = (lane >> 4) << 3;
  const float* Ab = A + (size_t)(row0 + r) * HDIM + ks;
  const float* Wb = W + (size_t)(col0 + r) * HDIM + ks;
  f32x4 acc[2][2] = {};

  float4 ca[2][2], cw[2][2];
#pragma unroll
  for (int mi = 0; mi < 2; ++mi) {
    const float* pa = Ab + (size_t)mi * 16 * HDIM;
    const float* pw = Wb + (size_t)mi * 16 * HDIM;
    ca[mi][0] = *(const float4*)pa;     ca[mi][1] = *(const float4*)(pa + 4);
    cw[mi][0] = *(const float4*)pw;     cw[mi][1] = *(const float4*)(pw + 4);
  }
#pragma unroll
  for (int kb = 0; kb < 8; ++kb) {
    float4 na[2][2], nw[2][2];
    if (kb < 7) {
      const int off = (kb + 1) * 32;
#pragma unroll
      for (int mi = 0; mi < 2; ++mi) {
        const float* pa = Ab + (size_t)mi * 16 * HDIM + off;
        const float* pw = Wb + (size_t)mi * 16 * HDIM + off;
        na[mi][0] = *(const float4*)pa;  na[mi][1] = *(const float4*)(pa + 4);
        nw[mi][0] = *(const float4*)pw;  nw[mi][1] = *(const float4*)(pw + 4);
      }
    }
    bf16x8 af[2], wf[2];
#pragma unroll
    for (int mi = 0; mi < 2; ++mi) {
      af[mi][0]=(__bf16)ca[mi][0].x; af[mi][1]=(__bf16)ca[mi][0].y;
      af[mi][2]=(__bf16)ca[mi][0].z; af[mi][3]=(__bf16)ca[mi][0].w;
      af[mi][4]=(__bf16)ca[mi][1].x; af[mi][5]=(__bf16)ca[mi][1].y;
      af[mi][6]=(__bf16)ca[mi][1].z; af[mi][7]=(__bf16)ca[mi][1].w;
      wf[mi][0]=(__bf16)cw[mi][0].x; wf[mi][1]=(__bf16)cw[mi][0].y;
      wf[mi][2]=(__bf16)cw[mi][0].z; wf[mi][3]=(__bf16)cw[mi][0].w;
      wf[mi][4]=(__bf16)cw[mi][1].x; wf[mi][5]=(__bf16)cw[mi][1].y;
      wf[mi][6]=(__bf16)cw[mi][1].z; wf[mi][7]=(__bf16)cw[mi][1].w;
    }
#pragma unroll
    for (int mi = 0; mi < 2; ++mi)
#pragma unroll
      for (int ni = 0; ni < 2; ++ni)
        acc[mi][ni] = __builtin_amdgcn_mfma_f32_16x16x32_bf16(
            af[mi], wf[ni], acc[mi][ni], 0, 0, 0);
    if (kb < 7) {
#pragma unroll
      for (int mi = 0; mi < 2; ++mi) {
        ca[mi][0]=na[mi][0]; ca[mi][1]=na[mi][1];
        cw[mi][0]=nw[mi][0]; cw[mi][1]=nw[mi][1];
      }
    }
  }
  const int crow = (lane >> 4) * 4;
  const int ccol = lane & 15;
#pragma unroll
  for (int mi = 0; mi < 2; ++mi)
#pragma unroll
    for (int ni = 0; ni < 2; ++ni) {
      const int oc = col0 + ni * 16 + ccol;
      const float bv = bias[oc];
#pragma unroll
      for (int rg = 0; rg < 4; ++rg)
        out[(size_t)(row0 + mi * 16 + crow + rg) * HDIM + oc] = acc[mi][ni][rg] + bv;
    }
}

// Fused q/k/v projection: grid (32, 8, 3), 256 threads = 4 tile-waves.
// wave w -> row-tile (bx*4+w) in [0,127), col-tile by. 3048 useful waves.
__global__ __launch_bounds__(256) void gemm_qkv(
    const float* __restrict__ q_in, const float* __restrict__ k_in,
    const float* __restrict__ v_in,
    const float* __restrict__ Wq, const float* __restrict__ bq,
    const float* __restrict__ Wk, const float* __restrict__ bk,
    const float* __restrict__ Wv, const float* __restrict__ bv,
    float* __restrict__ qp, float* __restrict__ kp, float* __restrict__ vp)
{
  const int w = threadIdx.x >> 6;
  const int tile = blockIdx.x * 4 + w;
  if (tile >= 127) return;
  const float* A; const float* W; const float* bias; float* o;
  if (blockIdx.z == 0)      { A = q_in; W = Wq; bias = bq; o = qp; }
  else if (blockIdx.z == 1) { A = k_in; W = Wk; bias = bk; o = kp; }
  else                      { A = v_in; W = Wv; bias = bv; o = vp; }
  gemm_tile32(A, W, bias, o, tile * 32, blockIdx.y * 32);
}

// Output projection: grid (32, 8), 256 threads = 4 tile-waves.
__global__ __launch_bounds__(256) void gemm_o(
    const float* __restrict__ A, const float* __restrict__ W,
    const float* __restrict__ bias, float* __restrict__ out)
{
  const int w = threadIdx.x >> 6;
  const int tile = blockIdx.x * 4 + w;
  if (tile >= 127) return;
  gemm_tile32(A, W, bias, out, tile * 32, blockIdx.y * 32);
}

// ---------------------------------------------------------------------------
// Fused sparse attention. One 256-thread block per (b,q); long-pole items
// (q<3, n~63) mapped to the first 96 blocks so they start first.
// ---------------------------------------------------------------------------
__global__ __launch_bounds__(256) void attn_kernel(
    const float* __restrict__ qp, const float* __restrict__ kp,
    const float* __restrict__ vp, const int* __restrict__ graph,
    const float* __restrict__ ekt, const float* __restrict__ evt,
    const float* __restrict__ eqt, float* __restrict__ xp)
{
  int b, q;
  {
    const int bx = blockIdx.x;
    if (bx < 96) { b = bx / 3; q = bx % 3; }
    else { const int rr = bx - 96; b = rr / 124; q = 3 + rr % 124; }
  }
  const int t = threadIdx.x;
  const int w = t >> 6;
  const int l = t & 63;

  __shared__ int   s_list[S_LEN];
  __shared__ float s_attn[4][S_LEN];
  __shared__ int   s_cnt[2];

  bool valid = false;
  const int k0 = w * 64 + l;
  if (w < 2 && k0 < S_LEN) {
    const int g = graph[((size_t)b * S_LEN + q) * S_LEN + k0];
    bool keep;
    if (q < 3 || k0 < 3) keep = true;
    else {
      const int blk = 3 + 2 * ((q - 3) >> 1);
      keep = (k0 >= blk) & (k0 < blk + 2);
    }
    valid = (g != 0) && keep;
  }
  const unsigned long long bal = __ballot(valid);
  if (w < 2 && l == 0) s_cnt[w] = (int)__popcll(bal);
  __syncthreads();
  int n = s_cnt[0] + s_cnt[1];
  if (valid) {
    const int pos = (int)__popcll(bal & ((1ull << l) - 1ull)) + (w ? s_cnt[0] : 0);
    s_list[pos] = k0;
  }
  __syncthreads();

  if (n == 0) {
    if (t < S_LEN) {
      s_list[t] = t;
      const float u = 1.0f / 127.0f;
      s_attn[0][t] = u; s_attn[1][t] = u; s_attn[2][t] = u; s_attn[3][t] = u;
    }
    n = S_LEN;
  } else {
    const float* qrow = qp + ((size_t)b * S_LEN + q) * HDIM;
    const float  q0 = qrow[l], q1 = qrow[64 + l], q2 = qrow[128 + l], q3 = qrow[192 + l];
    const float* eqb = eqt + ((size_t)b * S_LEN * S_LEN + q) * DH;
    const float* ekb = ekt + ((size_t)(b * S_LEN + q)) * S_LEN * DH;
    const float* kpb = kp + (size_t)b * S_LEN * HDIM;

    float ceq = 0.f, cek = 0.f, ck0 = 0.f, ck1 = 0.f, ck2 = 0.f, ck3 = 0.f;
    if (w < n) {
      const int kk = s_list[w];
      ceq = eqb[(size_t)kk * (S_LEN * DH) + l];
      cek = ekb[kk * DH + l];
      const float* kr = kpb + (size_t)kk * HDIM;
      ck0 = kr[l]; ck1 = kr[64 + l]; ck2 = kr[128 + l]; ck3 = kr[192 + l];
    }
    for (int i0 = 0; i0 < n; i0 += 4) {
      const int i = i0 + w;
      float neq = 0.f, nek = 0.f, nk0 = 0.f, nk1 = 0.f, nk2 = 0.f, nk3 = 0.f;
      const int j = i + 4;
      if (j < n) {
        const int kk = s_list[j];
        neq = eqb[(size_t)kk * (S_LEN * DH) + l];
        nek = ekb[kk * DH + l];
        const float* kr = kpb + (size_t)kk * HDIM;
        nk0 = kr[l]; nk1 = kr[64 + l]; nk2 = kr[128 + l]; nk3 = kr[192 + l];
      }
      float p0 = (q0 + ceq) * (ck0 + cek);
      float p1 = (q1 + ceq) * (ck1 + cek);
      float p2 = (q2 + ceq) * (ck2 + cek);
      float p3 = (q3 + ceq) * (ck3 + cek);
#pragma unroll
      for (int off = 32; off; off >>= 1) {
        p0 += __shfl_xor(p0, off, 64);
        p1 += __shfl_xor(p1, off, 64);
        p2 += __shfl_xor(p2, off, 64);
        p3 += __shfl_xor(p3, off, 64);
      }
      if (i < n && l < 4) {
        const float s = (l == 0) ? p0 : (l == 1) ? p1 : (l == 2) ? p2 : p3;
        s_attn[l][i] = s * SCALE_F;
      }
      ceq = neq; cek = nek; ck0 = nk0; ck1 = nk1; ck2 = nk2; ck3 = nk3;
    }
    __syncthreads();

    {
      const float v0 = (l < n) ? s_attn[w][l] : -INFINITY;
      const float v1 = (64 + l < n) ? s_attn[w][64 + l] : -INFINITY;
      float mx = fmaxf(v0, v1);
#pragma unroll
      for (int off = 32; off; off >>= 1) mx = fmaxf(mx, __shfl_xor(mx, off, 64));
      const float e0 = (l < n) ? expf(v0 - mx) : 0.f;
      const float e1 = (64 + l < n) ? expf(v1 - mx) : 0.f;
      float sm = e0 + e1;
#pragma unroll
      for (int off = 32; off; off >>= 1) sm += __shfl_xor(sm, off, 64);
      const float inv = 1.0f / sm;
      if (l < n) s_attn[w][l] = e0 * inv;
      if (64 + l < n) s_attn[w][64 + l] = e1 * inv;
    }
  }
  __syncthreads();

  {
    const float* evb = evt + ((size_t)(b * S_LEN + q)) * S_LEN * DH;
    const float* vbp = vp + (size_t)b * S_LEN * HDIM + w * DH;
    float acc0 = 0.f, acc1 = 0.f;
    int i = 0;
    for (; i + 4 <= n; i += 4) {
      const int ka = s_list[i], kb2 = s_list[i + 1];
      const int kc = s_list[i + 2], kd = s_list[i + 3];
      const float aa = s_attn[w][i],     ab = s_attn[w][i + 1];
      const float ac = s_attn[w][i + 2], ad = s_attn[w][i + 3];
      const float va = vbp[(size_t)ka * HDIM + l],   ea = evb[ka * DH + l];
      const float vb2 = vbp[(size_t)kb2 * HDIM + l], eb = evb[kb2 * DH + l];
      const float vc = vbp[(size_t)kc * HDIM + l],   ec = evb[kc * DH + l];
      const float vd = vbp[(size_t)kd * HDIM + l],   ed = evb[kd * DH + l];
      acc0 += aa * (va + ea) + ab * (vb2 + eb);
      acc1 += ac * (vc + ec) + ad * (vd + ed);
    }
    for (; i < n; ++i) {
      const int kk = s_list[i];
      acc0 += s_attn[w][i] * (vbp[(size_t)kk * HDIM + l] + evb[kk * DH + l]);
    }
    xp[((size_t)b * S_LEN + q) * HDIM + t] = acc0 + acc1;
  }
}

extern "C" void kernel_launch(void* const* d_in, const int* in_sizes, int n_in,
                              void* d_out, int out_size, void* d_ws, size_t ws_size,
                              hipStream_t stream) {
  const float* query = (const float*)d_in[0];
  const float* key   = (const float*)d_in[1];
  const float* value = (const float*)d_in[2];
  const int*   graph = (const int*)d_in[3];
  const float* ekt   = (const float*)d_in[4];
  const float* evt   = (const float*)d_in[5];
  const float* eqt   = (const float*)d_in[6];
  const float* Wq = (const float*)d_in[7];  const float* bq = (const float*)d_in[8];
  const float* Wk = (const float*)d_in[9];  const float* bk = (const float*)d_in[10];
  const float* Wv = (const float*)d_in[11]; const float* bv = (const float*)d_in[12];
  const float* Wo = (const float*)d_in[13]; const float* bo = (const float*)d_in[14];
  float* out = (float*)d_out;

  const size_t NTOK = (size_t)NB * S_LEN;  // 4064
  float* qp = (float*)d_ws;
  float* kp = qp + NTOK * HDIM;
  float* vp = kp + NTOK * HDIM;
  float* xp = vp + NTOK * HDIM;

  gemm_qkv<<<dim3(32, 8, 3), 256, 0, stream>>>(query, key, value,
                                               Wq, bq, Wk, bk, Wv, bv,
                                               qp, kp, vp);
  attn_kernel<<<dim3(NB * S_LEN), 256, 0, stream>>>(qp, kp, vp, graph,
                                                    ekt, evt, eqt, xp);
  gemm_o<<<dim3(32, 8), 256, 0, stream>>>(xp, Wo, bo, out);
}

// Round 5
// 54.342 us; speedup vs baseline: 9.6388x; 1.1561x over previous
//
#include <hip/hip_runtime.h>
#include <hip/hip_bf16.h>

#define S_LEN 127
#define NB    32
#define HDIM  256
#define DH    64
#define SCALE_F 0.125f

typedef __bf16 bf16x8 __attribute__((ext_vector_type(8)));
typedef __bf16 bf16x4 __attribute__((ext_vector_type(4)));
typedef float  f32x4  __attribute__((ext_vector_type(4)));

#define NTOK  4064                 // NB * S_LEN
#define NQKV4 260096               // NTOK*HDIM/4 float4 groups per q/k/v
#define NW4   16384                // 256*256/4 float4 groups per W

// ---------------------------------------------------------------------------
// One-pass f32 -> bf16 conversion of q/k/v inputs and all four weights.
// Pure streaming, ~20 MB traffic. Removes ALL cvt VALU from the GEMM loops.
// ---------------------------------------------------------------------------
__global__ __launch_bounds__(256) void convert_bf16(
    const float* __restrict__ q, const float* __restrict__ k,
    const float* __restrict__ v,
    const float* __restrict__ Wq, const float* __restrict__ Wk,
    const float* __restrict__ Wv, const float* __restrict__ Wo,
    __bf16* __restrict__ qb, __bf16* __restrict__ kb, __bf16* __restrict__ vb,
    __bf16* __restrict__ Wqb, __bf16* __restrict__ Wkb,
    __bf16* __restrict__ Wvb, __bf16* __restrict__ Wob)
{
  size_t t = (size_t)blockIdx.x * 256 + threadIdx.x;   // float4 index
  const float* src; __bf16* dst;
  if (t < NQKV4)               { src = q;  dst = qb;  }
  else if ((t -= NQKV4) < NQKV4) { src = k;  dst = kb;  }
  else if ((t -= NQKV4) < NQKV4) { src = v;  dst = vb;  }
  else if ((t -= NQKV4) < NW4)   { src = Wq; dst = Wqb; }
  else if ((t -= NW4) < NW4)     { src = Wk; dst = Wkb; }
  else if ((t -= NW4) < NW4)     { src = Wv; dst = Wvb; }
  else if ((t -= NW4) < NW4)     { src = Wo; dst = Wob; }
  else return;
  const float4 x = ((const float4*)src)[t];
  bf16x4 r;
  r[0] = (__bf16)x.x; r[1] = (__bf16)x.y; r[2] = (__bf16)x.z; r[3] = (__bf16)x.w;
  ((bf16x4*)dst)[t] = r;
}

// ---------------------------------------------------------------------------
// Per-wave 32x32 tile of out[M,256] = A[M,256] @ W[256,256]^T + bias,
// A and W already bf16. 8 k-steps x (4 x 16B loads + 4 MFMA), 1-step
// lookahead prefetch. Zero conversion VALU in the loop.
// ---------------------------------------------------------------------------
__device__ __forceinline__ void gemm_tile32_bf16(
    const __bf16* __restrict__ A, const __bf16* __restrict__ W,
    const float* __restrict__ bias, float* __restrict__ out,
    int row0, int col0)
{
  const int lane = threadIdx.x & 63;
  const int r  = lane & 15;
  const int ks = (lane >> 4) << 3;
  const __bf16* Ab = A + (size_t)(row0 + r) * HDIM + ks;
  const __bf16* Wb = W + (size_t)(col0 + r) * HDIM + ks;
  f32x4 acc[2][2] = {};

  bf16x8 ca[2], cw[2];
  ca[0] = *(const bf16x8*)Ab;
  ca[1] = *(const bf16x8*)(Ab + (size_t)16 * HDIM);
  cw[0] = *(const bf16x8*)Wb;
  cw[1] = *(const bf16x8*)(Wb + (size_t)16 * HDIM);
#pragma unroll
  for (int kb = 0; kb < 8; ++kb) {
    bf16x8 na[2], nw[2];
    if (kb < 7) {
      const int off = (kb + 1) * 32;
      na[0] = *(const bf16x8*)(Ab + off);
      na[1] = *(const bf16x8*)(Ab + (size_t)16 * HDIM + off);
      nw[0] = *(const bf16x8*)(Wb + off);
      nw[1] = *(const bf16x8*)(Wb + (size_t)16 * HDIM + off);
    }
#pragma unroll
    for (int mi = 0; mi < 2; ++mi)
#pragma unroll
      for (int ni = 0; ni < 2; ++ni)
        acc[mi][ni] = __builtin_amdgcn_mfma_f32_16x16x32_bf16(
            ca[mi], cw[ni], acc[mi][ni], 0, 0, 0);
    if (kb < 7) {
      ca[0] = na[0]; ca[1] = na[1];
      cw[0] = nw[0]; cw[1] = nw[1];
    }
  }
  const int crow = (lane >> 4) * 4;
  const int ccol = lane & 15;
#pragma unroll
  for (int mi = 0; mi < 2; ++mi)
#pragma unroll
    for (int ni = 0; ni < 2; ++ni) {
      const int oc = col0 + ni * 16 + ccol;
      const float bv = bias[oc];
#pragma unroll
      for (int rg = 0; rg < 4; ++rg)
        out[(size_t)(row0 + mi * 16 + crow + rg) * HDIM + oc] = acc[mi][ni][rg] + bv;
    }
}

// Fused q/k/v projection: grid (32, 8, 3), 256 threads = 4 tile-waves.
__global__ __launch_bounds__(256) void gemm_qkv(
    const __bf16* __restrict__ qb, const __bf16* __restrict__ kb,
    const __bf16* __restrict__ vb,
    const __bf16* __restrict__ Wqb, const float* __restrict__ bq,
    const __bf16* __restrict__ Wkb, const float* __restrict__ bk,
    const __bf16* __restrict__ Wvb, const float* __restrict__ bv,
    float* __restrict__ qp, float* __restrict__ kp, float* __restrict__ vp)
{
  const int w = threadIdx.x >> 6;
  const int tile = blockIdx.x * 4 + w;
  if (tile >= 127) return;
  const __bf16* A; const __bf16* W; const float* bias; float* o;
  if (blockIdx.z == 0)      { A = qb; W = Wqb; bias = bq; o = qp; }
  else if (blockIdx.z == 1) { A = kb; W = Wkb; bias = bk; o = kp; }
  else                      { A = vb; W = Wvb; bias = bv; o = vp; }
  gemm_tile32_bf16(A, W, bias, o, tile * 32, blockIdx.y * 32);
}

// Output projection: grid (32, 8), 256 threads = 4 tile-waves.
__global__ __launch_bounds__(256) void gemm_o(
    const __bf16* __restrict__ A, const __bf16* __restrict__ W,
    const float* __restrict__ bias, float* __restrict__ out)
{
  const int w = threadIdx.x >> 6;
  const int tile = blockIdx.x * 4 + w;
  if (tile >= 127) return;
  gemm_tile32_bf16(A, W, bias, out, tile * 32, blockIdx.y * 32);
}

// ---------------------------------------------------------------------------
// Fused sparse attention (R4-proven). One 256-thread block per (b,q);
// long-pole items (q<3, n~63) mapped to the first 96 blocks.
// Writes x as bf16 for the pure-bf16 out-projection.
// ---------------------------------------------------------------------------
__global__ __launch_bounds__(256) void attn_kernel(
    const float* __restrict__ qp, const float* __restrict__ kp,
    const float* __restrict__ vp, const int* __restrict__ graph,
    const float* __restrict__ ekt, const float* __restrict__ evt,
    const float* __restrict__ eqt, __bf16* __restrict__ xpb)
{
  int b, q;
  {
    const int bx = blockIdx.x;
    if (bx < 96) { b = bx / 3; q = bx % 3; }
    else { const int rr = bx - 96; b = rr / 124; q = 3 + rr % 124; }
  }
  const int t = threadIdx.x;
  const int w = t >> 6;
  const int l = t & 63;

  __shared__ int   s_list[S_LEN];
  __shared__ float s_attn[4][S_LEN];
  __shared__ int   s_cnt[2];

  bool valid = false;
  const int k0 = w * 64 + l;
  if (w < 2 && k0 < S_LEN) {
    const int g = graph[((size_t)b * S_LEN + q) * S_LEN + k0];
    bool keep;
    if (q < 3 || k0 < 3) keep = true;
    else {
      const int blk = 3 + 2 * ((q - 3) >> 1);
      keep = (k0 >= blk) & (k0 < blk + 2);
    }
    valid = (g != 0) && keep;
  }
  const unsigned long long bal = __ballot(valid);
  if (w < 2 && l == 0) s_cnt[w] = (int)__popcll(bal);
  __syncthreads();
  int n = s_cnt[0] + s_cnt[1];
  if (valid) {
    const int pos = (int)__popcll(bal & ((1ull << l) - 1ull)) + (w ? s_cnt[0] : 0);
    s_list[pos] = k0;
  }
  __syncthreads();

  if (n == 0) {
    if (t < S_LEN) {
      s_list[t] = t;
      const float u = 1.0f / 127.0f;
      s_attn[0][t] = u; s_attn[1][t] = u; s_attn[2][t] = u; s_attn[3][t] = u;
    }
    n = S_LEN;
  } else {
    const float* qrow = qp + ((size_t)b * S_LEN + q) * HDIM;
    const float  q0 = qrow[l], q1 = qrow[64 + l], q2 = qrow[128 + l], q3 = qrow[192 + l];
    const float* eqb = eqt + ((size_t)b * S_LEN * S_LEN + q) * DH;
    const float* ekb = ekt + ((size_t)(b * S_LEN + q)) * S_LEN * DH;
    const float* kpb = kp + (size_t)b * S_LEN * HDIM;

    float ceq = 0.f, cek = 0.f, ck0 = 0.f, ck1 = 0.f, ck2 = 0.f, ck3 = 0.f;
    if (w < n) {
      const int kk = s_list[w];
      ceq = eqb[(size_t)kk * (S_LEN * DH) + l];
      cek = ekb[kk * DH + l];
      const float* kr = kpb + (size_t)kk * HDIM;
      ck0 = kr[l]; ck1 = kr[64 + l]; ck2 = kr[128 + l]; ck3 = kr[192 + l];
    }
    for (int i0 = 0; i0 < n; i0 += 4) {
      const int i = i0 + w;
      float neq = 0.f, nek = 0.f, nk0 = 0.f, nk1 = 0.f, nk2 = 0.f, nk3 = 0.f;
      const int j = i + 4;
      if (j < n) {
        const int kk = s_list[j];
        neq = eqb[(size_t)kk * (S_LEN * DH) + l];
        nek = ekb[kk * DH + l];
        const float* kr = kpb + (size_t)kk * HDIM;
        nk0 = kr[l]; nk1 = kr[64 + l]; nk2 = kr[128 + l]; nk3 = kr[192 + l];
      }
      float p0 = (q0 + ceq) * (ck0 + cek);
      float p1 = (q1 + ceq) * (ck1 + cek);
      float p2 = (q2 + ceq) * (ck2 + cek);
      float p3 = (q3 + ceq) * (ck3 + cek);
#pragma unroll
      for (int off = 32; off; off >>= 1) {
        p0 += __shfl_xor(p0, off, 64);
        p1 += __shfl_xor(p1, off, 64);
        p2 += __shfl_xor(p2, off, 64);
        p3 += __shfl_xor(p3, off, 64);
      }
      if (i < n && l < 4) {
        const float s = (l == 0) ? p0 : (l == 1) ? p1 : (l == 2) ? p2 : p3;
        s_attn[l][i] = s * SCALE_F;
      }
      ceq = neq; cek = nek; ck0 = nk0; ck1 = nk1; ck2 = nk2; ck3 = nk3;
    }
    __syncthreads();

    {
      const float v0 = (l < n) ? s_attn[w][l] : -INFINITY;
      const float v1 = (64 + l < n) ? s_attn[w][64 + l] : -INFINITY;
      float mx = fmaxf(v0, v1);
#pragma unroll
      for (int off = 32; off; off >>= 1) mx = fmaxf(mx, __shfl_xor(mx, off, 64));
      const float e0 = (l < n) ? expf(v0 - mx) : 0.f;
      const float e1 = (64 + l < n) ? expf(v1 - mx) : 0.f;
      float sm = e0 + e1;
#pragma unroll
      for (int off = 32; off; off >>= 1) sm += __shfl_xor(sm, off, 64);
      const float inv = 1.0f / sm;
      if (l < n) s_attn[w][l] = e0 * inv;
      if (64 + l < n) s_attn[w][64 + l] = e1 * inv;
    }
  }
  __syncthreads();

  {
    const float* evb = evt + ((size_t)(b * S_LEN + q)) * S_LEN * DH;
    const float* vbp = vp + (size_t)b * S_LEN * HDIM + w * DH;
    float acc0 = 0.f, acc1 = 0.f;
    int i = 0;
    for (; i + 4 <= n; i += 4) {
      const int ka = s_list[i], kb2 = s_list[i + 1];
      const int kc = s_list[i + 2], kd = s_list[i + 3];
      const float aa = s_attn[w][i],     ab = s_attn[w][i + 1];
      const float ac = s_attn[w][i + 2], ad = s_attn[w][i + 3];
      const float va = vbp[(size_t)ka * HDIM + l],   ea = evb[ka * DH + l];
      const float vb2 = vbp[(size_t)kb2 * HDIM + l], eb = evb[kb2 * DH + l];
      const float vc = vbp[(size_t)kc * HDIM + l],   ec = evb[kc * DH + l];
      const float vd = vbp[(size_t)kd * HDIM + l],   ed = evb[kd * DH + l];
      acc0 += aa * (va + ea) + ab * (vb2 + eb);
      acc1 += ac * (vc + ec) + ad * (vd + ed);
    }
    for (; i < n; ++i) {
      const int kk = s_list[i];
      acc0 += s_attn[w][i] * (vbp[(size_t)kk * HDIM + l] + evb[kk * DH + l]);
    }
    xpb[((size_t)b * S_LEN + q) * HDIM + t] = (__bf16)(acc0 + acc1);
  }
}

extern "C" void kernel_launch(void* const* d_in, const int* in_sizes, int n_in,
                              void* d_out, int out_size, void* d_ws, size_t ws_size,
                              hipStream_t stream) {
  const float* query = (const float*)d_in[0];
  const float* key   = (const float*)d_in[1];
  const float* value = (const float*)d_in[2];
  const int*   graph = (const int*)d_in[3];
  const float* ekt   = (const float*)d_in[4];
  const float* evt   = (const float*)d_in[5];
  const float* eqt   = (const float*)d_in[6];
  const float* Wq = (const float*)d_in[7];  const float* bq = (const float*)d_in[8];
  const float* Wk = (const float*)d_in[9];  const float* bk = (const float*)d_in[10];
  const float* Wv = (const float*)d_in[11]; const float* bv = (const float*)d_in[12];
  const float* Wo = (const float*)d_in[13]; const float* bo = (const float*)d_in[14];
  float* out = (float*)d_out;

  const size_t NE = (size_t)NTOK * HDIM;   // 1,040,384 elems
  char* p = (char*)d_ws;
  float* qp = (float*)p;            p += NE * 4;
  float* kp = (float*)p;            p += NE * 4;
  float* vp = (float*)p;            p += NE * 4;
  __bf16* qb  = (__bf16*)p;         p += NE * 2;
  __bf16* kb  = (__bf16*)p;         p += NE * 2;
  __bf16* vb  = (__bf16*)p;         p += NE * 2;
  __bf16* xpb = (__bf16*)p;         p += NE * 2;
  __bf16* Wqb = (__bf16*)p;         p += (size_t)HDIM * HDIM * 2;
  __bf16* Wkb = (__bf16*)p;         p += (size_t)HDIM * HDIM * 2;
  __bf16* Wvb = (__bf16*)p;         p += (size_t)HDIM * HDIM * 2;
  __bf16* Wob = (__bf16*)p;

  // total float4 groups: 3*260096 + 4*16384 = 845,824 -> 3304 blocks
  convert_bf16<<<dim3(3304), 256, 0, stream>>>(query, key, value,
                                               Wq, Wk, Wv, Wo,
                                               qb, kb, vb, Wqb, Wkb, Wvb, Wob);
  gemm_qkv<<<dim3(32, 8, 3), 256, 0, stream>>>(qb, kb, vb,
                                               Wqb, bq, Wkb, bk, Wvb, bv,
                                               qp, kp, vp);
  attn_kernel<<<dim3(NB * S_LEN), 256, 0, stream>>>(qp, kp, vp, graph,
                                                    ekt, evt, eqt, xpb);
  gemm_o<<<dim3(32, 8), 256, 0, stream>>>(xpb, Wob, bo, out);
}

// Round 6
// 52.761 us; speedup vs baseline: 9.9275x; 1.0300x over previous
//
#include <hip/hip_runtime.h>
#include <hip/hip_bf16.h>

#define S_LEN 127
#define NB    32
#define HDIM  256
#define DH    64
#define SCALE_F 0.125f

typedef __bf16 bf16x8 __attribute__((ext_vector_type(8)));
typedef __bf16 bf16x4 __attribute__((ext_vector_type(4)));
typedef float  f32x4  __attribute__((ext_vector_type(4)));

#define NTOK  4064                 // NB * S_LEN
#define NQKV4 260096               // NTOK*HDIM/4 float4 groups per q/k/v
#define NW4   16384                // 256*256/4 float4 groups per W

// ---------------------------------------------------------------------------
// One-pass f32 -> bf16 conversion of q/k/v inputs and all four weights.
// ---------------------------------------------------------------------------
__global__ __launch_bounds__(256) void convert_bf16(
    const float* __restrict__ q, const float* __restrict__ k,
    const float* __restrict__ v,
    const float* __restrict__ Wq, const float* __restrict__ Wk,
    const float* __restrict__ Wv, const float* __restrict__ Wo,
    __bf16* __restrict__ qb, __bf16* __restrict__ kb, __bf16* __restrict__ vb,
    __bf16* __restrict__ Wqb, __bf16* __restrict__ Wkb,
    __bf16* __restrict__ Wvb, __bf16* __restrict__ Wob)
{
  size_t t = (size_t)blockIdx.x * 256 + threadIdx.x;   // float4 index
  const float* src; __bf16* dst;
  if (t < NQKV4)               { src = q;  dst = qb;  }
  else if ((t -= NQKV4) < NQKV4) { src = k;  dst = kb;  }
  else if ((t -= NQKV4) < NQKV4) { src = v;  dst = vb;  }
  else if ((t -= NQKV4) < NW4)   { src = Wq; dst = Wqb; }
  else if ((t -= NW4) < NW4)     { src = Wk; dst = Wkb; }
  else if ((t -= NW4) < NW4)     { src = Wv; dst = Wvb; }
  else if ((t -= NW4) < NW4)     { src = Wo; dst = Wob; }
  else return;
  const float4 x = ((const float4*)src)[t];
  bf16x4 r;
  r[0] = (__bf16)x.x; r[1] = (__bf16)x.y; r[2] = (__bf16)x.z; r[3] = (__bf16)x.w;
  ((bf16x4*)dst)[t] = r;
}

// ---------------------------------------------------------------------------
// Per-wave 32x32 tile, pure-bf16 operands (R5-proven).
// ---------------------------------------------------------------------------
__device__ __forceinline__ void gemm_tile32_bf16(
    const __bf16* __restrict__ A, const __bf16* __restrict__ W,
    const float* __restrict__ bias, float* __restrict__ out,
    int row0, int col0)
{
  const int lane = threadIdx.x & 63;
  const int r  = lane & 15;
  const int ks = (lane >> 4) << 3;
  const __bf16* Ab = A + (size_t)(row0 + r) * HDIM + ks;
  const __bf16* Wb = W + (size_t)(col0 + r) * HDIM + ks;
  f32x4 acc[2][2] = {};

  bf16x8 ca[2], cw[2];
  ca[0] = *(const bf16x8*)Ab;
  ca[1] = *(const bf16x8*)(Ab + (size_t)16 * HDIM);
  cw[0] = *(const bf16x8*)Wb;
  cw[1] = *(const bf16x8*)(Wb + (size_t)16 * HDIM);
#pragma unroll
  for (int kb = 0; kb < 8; ++kb) {
    bf16x8 na[2], nw[2];
    if (kb < 7) {
      const int off = (kb + 1) * 32;
      na[0] = *(const bf16x8*)(Ab + off);
      na[1] = *(const bf16x8*)(Ab + (size_t)16 * HDIM + off);
      nw[0] = *(const bf16x8*)(Wb + off);
      nw[1] = *(const bf16x8*)(Wb + (size_t)16 * HDIM + off);
    }
#pragma unroll
    for (int mi = 0; mi < 2; ++mi)
#pragma unroll
      for (int ni = 0; ni < 2; ++ni)
        acc[mi][ni] = __builtin_amdgcn_mfma_f32_16x16x32_bf16(
            ca[mi], cw[ni], acc[mi][ni], 0, 0, 0);
    if (kb < 7) {
      ca[0] = na[0]; ca[1] = na[1];
      cw[0] = nw[0]; cw[1] = nw[1];
    }
  }
  const int crow = (lane >> 4) * 4;
  const int ccol = lane & 15;
#pragma unroll
  for (int mi = 0; mi < 2; ++mi)
#pragma unroll
    for (int ni = 0; ni < 2; ++ni) {
      const int oc = col0 + ni * 16 + ccol;
      const float bv = bias[oc];
#pragma unroll
      for (int rg = 0; rg < 4; ++rg)
        out[(size_t)(row0 + mi * 16 + crow + rg) * HDIM + oc] = acc[mi][ni][rg] + bv;
    }
}

__global__ __launch_bounds__(256) void gemm_qkv(
    const __bf16* __restrict__ qb, const __bf16* __restrict__ kb,
    const __bf16* __restrict__ vb,
    const __bf16* __restrict__ Wqb, const float* __restrict__ bq,
    const __bf16* __restrict__ Wkb, const float* __restrict__ bk,
    const __bf16* __restrict__ Wvb, const float* __restrict__ bv,
    float* __restrict__ qp, float* __restrict__ kp, float* __restrict__ vp)
{
  const int w = threadIdx.x >> 6;
  const int tile = blockIdx.x * 4 + w;
  if (tile >= 127) return;
  const __bf16* A; const __bf16* W; const float* bias; float* o;
  if (blockIdx.z == 0)      { A = qb; W = Wqb; bias = bq; o = qp; }
  else if (blockIdx.z == 1) { A = kb; W = Wkb; bias = bk; o = kp; }
  else                      { A = vb; W = Wvb; bias = bv; o = vp; }
  gemm_tile32_bf16(A, W, bias, o, tile * 32, blockIdx.y * 32);
}

__global__ __launch_bounds__(256) void gemm_o(
    const __bf16* __restrict__ A, const __bf16* __restrict__ W,
    const float* __restrict__ bias, float* __restrict__ out)
{
  const int w = threadIdx.x >> 6;
  const int tile = blockIdx.x * 4 + w;
  if (tile >= 127) return;
  gemm_tile32_bf16(A, W, bias, out, tile * 32, blockIdx.y * 32);
}

// ---------------------------------------------------------------------------
// Fused sparse attention, 16-lane-group-per-column layout.
// Scores: 16 columns/block-iter, float4 loads, 4-level group reduce.
// PV: 4 columns/wave-iter, float4 loads, 2-level cross-group reduce.
// ---------------------------------------------------------------------------
__global__ __launch_bounds__(256) void attn_kernel(
    const float* __restrict__ qp, const float* __restrict__ kp,
    const float* __restrict__ vp, const int* __restrict__ graph,
    const float* __restrict__ ekt, const float* __restrict__ evt,
    const float* __restrict__ eqt, __bf16* __restrict__ xpb)
{
  int b, q;
  {
    const int bx = blockIdx.x;
    if (bx < 96) { b = bx / 3; q = bx % 3; }
    else { const int rr = bx - 96; b = rr / 124; q = 3 + rr % 124; }
  }
  const int t = threadIdx.x;
  const int w = t >> 6;        // wave 0..3
  const int l = t & 63;        // lane
  const int ll = l & 15;       // d-group: d = ll*4 .. ll*4+3
  const int g  = l >> 4;       // column slot 0..3

  __shared__ int   s_list[S_LEN];
  __shared__ float s_attn[4][S_LEN];
  __shared__ int   s_cnt[2];

  // ---- compacted valid-k list (waves 0,1; deterministic ballot) ----
  bool valid = false;
  const int k0 = w * 64 + l;
  if (w < 2 && k0 < S_LEN) {
    const int gr = graph[((size_t)b * S_LEN + q) * S_LEN + k0];
    bool keep;
    if (q < 3 || k0 < 3) keep = true;
    else {
      const int blk = 3 + 2 * ((q - 3) >> 1);
      keep = (k0 >= blk) & (k0 < blk + 2);
    }
    valid = (gr != 0) && keep;
  }
  const unsigned long long bal = __ballot(valid);
  if (w < 2 && l == 0) s_cnt[w] = (int)__popcll(bal);
  __syncthreads();
  int n = s_cnt[0] + s_cnt[1];
  if (valid) {
    const int pos = (int)__popcll(bal & ((1ull << l) - 1ull)) + (w ? s_cnt[0] : 0);
    s_list[pos] = k0;
  }
  __syncthreads();

  if (n == 0) {
    // all columns masked -> exact uniform 1/127
    if (t < S_LEN) {
      s_list[t] = t;
      const float u = 1.0f / 127.0f;
      s_attn[0][t] = u; s_attn[1][t] = u; s_attn[2][t] = u; s_attn[3][t] = u;
    }
    n = S_LEN;
  } else {
    // ---- scores: group (w,g) owns column i0 + w*4 + g ----
    const float* qrow = qp + ((size_t)b * S_LEN + q) * HDIM;
    float4 q4[4];
#pragma unroll
    for (int h = 0; h < 4; ++h)
      q4[h] = *(const float4*)(qrow + h * 64 + ll * 4);
    const float* eqb = eqt + ((size_t)b * S_LEN * S_LEN + q) * DH;   // + k*S*DH
    const float* ekb = ekt + ((size_t)(b * S_LEN + q)) * S_LEN * DH; // + k*DH
    const float* kpb = kp + (size_t)b * S_LEN * HDIM;

    for (int i0 = 0; i0 < n; i0 += 16) {
      const int i = i0 + w * 4 + g;
      float p0 = 0.f, p1 = 0.f, p2 = 0.f, p3 = 0.f;
      if (i < n) {
        const int kk = s_list[i];
        const float4 eq4 = *(const float4*)(eqb + (size_t)kk * (S_LEN * DH) + ll * 4);
        const float4 ek4 = *(const float4*)(ekb + kk * DH + ll * 4);
        const float* kr = kpb + (size_t)kk * HDIM + ll * 4;
        const float4 kh0 = *(const float4*)(kr);
        const float4 kh1 = *(const float4*)(kr + 64);
        const float4 kh2 = *(const float4*)(kr + 128);
        const float4 kh3 = *(const float4*)(kr + 192);
        const float tx = ek4.x, ty = ek4.y, tz = ek4.z, tw = ek4.w;
        const float s0x = q4[0].x + eq4.x, s0y = q4[0].y + eq4.y,
                    s0z = q4[0].z + eq4.z, s0w = q4[0].w + eq4.w;
        const float s1x = q4[1].x + eq4.x, s1y = q4[1].y + eq4.y,
                    s1z = q4[1].z + eq4.z, s1w = q4[1].w + eq4.w;
        const float s2x = q4[2].x + eq4.x, s2y = q4[2].y + eq4.y,
                    s2z = q4[2].z + eq4.z, s2w = q4[2].w + eq4.w;
        const float s3x = q4[3].x + eq4.x, s3y = q4[3].y + eq4.y,
                    s3z = q4[3].z + eq4.z, s3w = q4[3].w + eq4.w;
        p0 = s0x*(kh0.x+tx) + s0y*(kh0.y+ty) + s0z*(kh0.z+tz) + s0w*(kh0.w+tw);
        p1 = s1x*(kh1.x+tx) + s1y*(kh1.y+ty) + s1z*(kh1.z+tz) + s1w*(kh1.w+tw);
        p2 = s2x*(kh2.x+tx) + s2y*(kh2.y+ty) + s2z*(kh2.z+tz) + s2w*(kh2.w+tw);
        p3 = s3x*(kh3.x+tx) + s3y*(kh3.y+ty) + s3z*(kh3.z+tz) + s3w*(kh3.w+tw);
      }
#pragma unroll
      for (int off = 1; off < 16; off <<= 1) {
        p0 += __shfl_xor(p0, off, 64);
        p1 += __shfl_xor(p1, off, 64);
        p2 += __shfl_xor(p2, off, 64);
        p3 += __shfl_xor(p3, off, 64);
      }
      if (i < n && ll < 4) {
        const float s = (ll == 0) ? p0 : (ll == 1) ? p1 : (ll == 2) ? p2 : p3;
        s_attn[ll][i] = s * SCALE_F;
      }
    }
    __syncthreads();

    // ---- softmax per head: wave w over n compacted scores ----
    {
      const float v0 = (l < n) ? s_attn[w][l] : -INFINITY;
      const float v1 = (64 + l < n) ? s_attn[w][64 + l] : -INFINITY;
      float mx = fmaxf(v0, v1);
#pragma unroll
      for (int off = 32; off; off >>= 1) mx = fmaxf(mx, __shfl_xor(mx, off, 64));
      const float e0 = (l < n) ? expf(v0 - mx) : 0.f;
      const float e1 = (64 + l < n) ? expf(v1 - mx) : 0.f;
      float sm = e0 + e1;
#pragma unroll
      for (int off = 32; off; off >>= 1) sm += __shfl_xor(sm, off, 64);
      const float inv = 1.0f / sm;
      if (l < n) s_attn[w][l] = e0 * inv;
      if (64 + l < n) s_attn[w][64 + l] = e1 * inv;
    }
  }
  __syncthreads();

  // ---- PV: wave w = head w; group g handles columns i0+g; lane = 4 d's ----
  {
    const float* evb = evt + ((size_t)(b * S_LEN + q)) * S_LEN * DH;
    const float* vbp = vp + (size_t)b * S_LEN * HDIM + w * DH + ll * 4;
    float ax = 0.f, ay = 0.f, az = 0.f, aw = 0.f;
    for (int i0 = 0; i0 < n; i0 += 4) {
      const int i = i0 + g;
      if (i < n) {
        const int kk = s_list[i];
        const float a = s_attn[w][i];
        const float4 v4 = *(const float4*)(vbp + (size_t)kk * HDIM);
        const float4 e4 = *(const float4*)(evb + kk * DH + ll * 4);
        ax += a * (v4.x + e4.x);
        ay += a * (v4.y + e4.y);
        az += a * (v4.z + e4.z);
        aw += a * (v4.w + e4.w);
      }
    }
#pragma unroll
    for (int off = 16; off < 64; off <<= 1) {
      ax += __shfl_xor(ax, off, 64);
      ay += __shfl_xor(ay, off, 64);
      az += __shfl_xor(az, off, 64);
      aw += __shfl_xor(aw, off, 64);
    }
    if (g == 0) {
      bf16x4 r;
      r[0] = (__bf16)ax; r[1] = (__bf16)ay; r[2] = (__bf16)az; r[3] = (__bf16)aw;
      *(bf16x4*)(xpb + ((size_t)b * S_LEN + q) * HDIM + w * 64 + ll * 4) = r;
    }
  }
}

extern "C" void kernel_launch(void* const* d_in, const int* in_sizes, int n_in,
                              void* d_out, int out_size, void* d_ws, size_t ws_size,
                              hipStream_t stream) {
  const float* query = (const float*)d_in[0];
  const float* key   = (const float*)d_in[1];
  const float* value = (const float*)d_in[2];
  const int*   graph = (const int*)d_in[3];
  const float* ekt   = (const float*)d_in[4];
  const float* evt   = (const float*)d_in[5];
  const float* eqt   = (const float*)d_in[6];
  const float* Wq = (const float*)d_in[7];  const float* bq = (const float*)d_in[8];
  const float* Wk = (const float*)d_in[9];  const float* bk = (const float*)d_in[10];
  const float* Wv = (const float*)d_in[11]; const float* bv = (const float*)d_in[12];
  const float* Wo = (const float*)d_in[13]; const float* bo = (const float*)d_in[14];
  float* out = (float*)d_out;

  const size_t NE = (size_t)NTOK * HDIM;   // 1,040,384 elems
  char* p = (char*)d_ws;
  float* qp = (float*)p;            p += NE * 4;
  float* kp = (float*)p;            p += NE * 4;
  float* vp = (float*)p;            p += NE * 4;
  __bf16* qb  = (__bf16*)p;         p += NE * 2;
  __bf16* kb  = (__bf16*)p;         p += NE * 2;
  __bf16* vb  = (__bf16*)p;         p += NE * 2;
  __bf16* xpb = (__bf16*)p;         p += NE * 2;
  __bf16* Wqb = (__bf16*)p;         p += (size_t)HDIM * HDIM * 2;
  __bf16* Wkb = (__bf16*)p;         p += (size_t)HDIM * HDIM * 2;
  __bf16* Wvb = (__bf16*)p;         p += (size_t)HDIM * HDIM * 2;
  __bf16* Wob = (__bf16*)p;

  convert_bf16<<<dim3(3304), 256, 0, stream>>>(query, key, value,
                                               Wq, Wk, Wv, Wo,
                                               qb, kb, vb, Wqb, Wkb, Wvb, Wob);
  gemm_qkv<<<dim3(32, 8, 3), 256, 0, stream>>>(qb, kb, vb,
                                               Wqb, bq, Wkb, bk, Wvb, bv,
                                               qp, kp, vp);
  attn_kernel<<<dim3(NB * S_LEN), 256, 0, stream>>>(qp, kp, vp, graph,
                                                    ekt, evt, eqt, xpb);
  gemm_o<<<dim3(32, 8), 256, 0, stream>>>(xpb, Wob, bo, out);
}